// Round 1
// baseline (921.457 us; speedup 1.0000x reference)
//
#include <hip/hip_runtime.h>
#include <hip/hip_fp16.h>

typedef _Float16 h2 __attribute__((ext_vector_type(2)));
typedef _Float16 half8 __attribute__((ext_vector_type(8)));
typedef float f32x4 __attribute__((ext_vector_type(4)));
typedef unsigned int u32;

#define B_ 256
#define T_ 512
#define F_ 256
#define H_ 512

// Per thread: 256 weight pairs total. 224 resident (VGPR+AGPR), 32 streamed from LDS.
#define NREG 224
#define NCH  (NREG / 4)   /* 56 uint4 chunks */
#define NLDS 32
#define LCH  (NLDS / 4)   /* 8 uint4 chunks; chunk ch -> q=ch, pairs 28..31 */

__device__ __forceinline__ float dot2f(u32 a, u32 b, float c) {
#if __has_builtin(__builtin_amdgcn_fdot2)
    return __builtin_amdgcn_fdot2(__builtin_bit_cast(h2, a), __builtin_bit_cast(h2, b), c, false);
#else
    h2 x = __builtin_bit_cast(h2, a), y = __builtin_bit_cast(h2, b);
    return c + (float)x[0] * (float)y[0] + (float)x[1] * (float)y[1];
#endif
}

__device__ __forceinline__ u32 packh2(float a, float b) {
    h2 v; v[0] = (_Float16)a; v[1] = (_Float16)b;
    return __builtin_bit_cast(u32, v);
}

__device__ __forceinline__ u32 pk2(float a, float b) {
#if __has_builtin(__builtin_amdgcn_cvt_pkrtz)
    return __builtin_bit_cast(u32, __builtin_amdgcn_cvt_pkrtz(a, b));
#else
    return packh2(a, b);
#endif
}

__device__ __forceinline__ float fast_tanh(float x) {
    float t = fminf(fmaxf(x, -12.f), 12.f);
    float s = __expf(2.f * t);
    return 1.f - 2.f * __builtin_amdgcn_rcpf(s + 1.f);
}

// Prepack regions (flat tid over 384*512 = 196608):
//   [0, 65536)        : Bg  — MFMA-fragment-ready Wx:
//                       J(ks,nt,l,j) = ((ks*32+nt)*64+l)*4+j
//                       value = pack(Wx[f][n], Wx[f+1][n]),
//                       f = ks*32 + (l>>4)*8 + 2j, n = nt*16 + (l&15)
//   [65536, 180224)   : greg — 56 uint4-chunks, i=4*i4+s in [0,224): q=i/28 p=i%28
//   [180224, 196608)  : glds — 8 uint4-chunks,  m=4*ch+s in [0,32):  q=ch   p=28+s
// rnn weight(i|m, t): w=t>>6 l=t&63 c=l+64q k0=64w+2p -> pack(Wh[k0][c], Wh[k0+1][c])
__global__ __launch_bounds__(512) void prepack_kernel(const float* __restrict__ Wx,
                                                      const float* __restrict__ Wh,
                                                      u32* __restrict__ Bg,
                                                      u32* __restrict__ greg,
                                                      u32* __restrict__ glds) {
    int id = blockIdx.x * 512 + threadIdx.x;
    if (id < 65536) {
        int j = id & 3, l = (id >> 2) & 63, nt = (id >> 8) & 31, ks = id >> 13;
        int f = ks * 32 + (l >> 4) * 8 + 2 * j;
        int n = nt * 16 + (l & 15);
        Bg[id] = packh2(Wx[f * H_ + n], Wx[(f + 1) * H_ + n]);
    } else if (id < 65536 + 114688) {
        int k = id - 65536;
        int s = k & 3, i4 = k >> 11, t = (k >> 2) & 511;
        int i = 4 * i4 + s;
        int q = i / 28, p = i % 28;
        int w = t >> 6, l = t & 63;
        int c = l + 64 * q, k0 = 64 * w + 2 * p;
        greg[k] = packh2(Wh[k0 * H_ + c], Wh[(k0 + 1) * H_ + c]);
    } else {
        int k = id - 65536 - 114688;
        int s = k & 3, ch = k >> 11, t = (k >> 2) & 511;
        int q = ch, p = 28 + s;
        int w = t >> 6, l = t & 63;
        int c = l + 64 * q, k0 = 64 * w + 2 * p;
        glds[k] = packh2(Wh[k0 * H_ + c], Wh[(k0 + 1) * H_ + c]);
    }
}

__device__ __forceinline__ void gload16(const uint4* g, uint4* l) {
    __builtin_amdgcn_global_load_lds((const __attribute__((address_space(1))) u32*)g,
                                     (__attribute__((address_space(3))) u32*)l, 16, 0, 0);
}

// MFMA GEMM: xp[row][n] = f16( sum_f x[row][f] * Wx[f][n] + b[n] )
// M = B*T = 131072, N = 512, K = 256. 128-row x 512-col tile per block (512 thr, 8 waves).
// Wave (rg = w>>1, cg = w&1): rows [32*rg, 32*rg+32) as 2 m-tiles, cols [256*cg, ...+256) as 16 n-tiles.
// A staged frag-ready in LDS (64 KB, read once); B double-buffered per k-step (2x32 KB) via
// global_load_lds from the fragment-ready prepack (linear dest = wave base + lane*16).
__global__ __launch_bounds__(512) void xp_mfma_kernel(const float* __restrict__ x,
                                                      const uint4* __restrict__ Bg,
                                                      const float* __restrict__ b,
                                                      __half* __restrict__ xp) {
    extern __shared__ u32 smem[];
    uint4* alds  = (uint4*)smem;      // 4096 uint4 = 64 KB
    uint4* bbuf0 = alds + 4096;       // 2048 uint4 = 32 KB
    uint4* bbuf1 = bbuf0 + 2048;      // 2048 uint4 = 32 KB

    const int tid  = threadIdx.x;
    const int lane = tid & 63;
    const int w    = tid >> 6;
    const int cg   = w & 1;
    const int rg   = w >> 1;
    const long row0 = (long)blockIdx.x * 128;

    // ---- stage B[ks=0] (async, linear) ----
#pragma unroll
    for (int it = 0; it < 4; ++it)
        gload16(Bg + it * 512 + tid, bbuf0 + it * 512 + tid);

    // ---- stage A fragment-ready: slot s=(rt,ks,l) -> x[rt*16+(l&15)][ks*32+(l>>4)*8 .. +8) ----
    const float4* x4 = (const float4*)(x + row0 * F_);
#pragma unroll
    for (int it = 0; it < 8; ++it) {
        int s  = it * 512 + tid;            // 0..4095
        int rt = s >> 9, ks = (s >> 6) & 7, l = s & 63;
        int row = rt * 16 + (l & 15);
        int f0  = ks * 32 + (l >> 4) * 8;
        float4 a = x4[row * 64 + (f0 >> 2)];
        float4 c = x4[row * 64 + (f0 >> 2) + 1];
        uint4 pv;
        pv.x = packh2(a.x, a.y); pv.y = packh2(a.z, a.w);
        pv.z = packh2(c.x, c.y); pv.w = packh2(c.z, c.w);
        alds[s] = pv;                       // sequential lanes -> conflict-free b128 writes
    }

    float bias[16];
#pragma unroll
    for (int nt = 0; nt < 16; ++nt) bias[nt] = b[cg * 256 + nt * 16 + (lane & 15)];

    f32x4 acc0[16], acc1[16];
#pragma unroll
    for (int nt = 0; nt < 16; ++nt) {
        acc0[nt] = (f32x4){0.f, 0.f, 0.f, 0.f};
        acc1[nt] = (f32x4){0.f, 0.f, 0.f, 0.f};
    }

    __syncthreads();  // drains vmcnt -> B[0] and A both resident

#pragma unroll
    for (int ks = 0; ks < 8; ++ks) {
        const uint4* blr = (ks & 1) ? bbuf1 : bbuf0;
        if (ks < 7) {
            uint4* bw = (ks & 1) ? bbuf0 : bbuf1;
            const uint4* gs = Bg + (ks + 1) * 2048;
#pragma unroll
            for (int it = 0; it < 4; ++it)
                gload16(gs + it * 512 + tid, bw + it * 512 + tid);
        }
        uint4 af0 = alds[((rg * 2 + 0) * 8 + ks) * 64 + lane];
        uint4 af1 = alds[((rg * 2 + 1) * 8 + ks) * 64 + lane];
        half8 a0 = __builtin_bit_cast(half8, af0);
        half8 a1 = __builtin_bit_cast(half8, af1);
#pragma unroll
        for (int nt = 0; nt < 16; ++nt) {
            uint4 bf = blr[(cg * 16 + nt) * 64 + lane];
            half8 bb = __builtin_bit_cast(half8, bf);
            acc0[nt] = __builtin_amdgcn_mfma_f32_16x16x32_f16(a0, bb, acc0[nt], 0, 0, 0);
            acc1[nt] = __builtin_amdgcn_mfma_f32_16x16x32_f16(a1, bb, acc1[nt], 0, 0, 0);
        }
        __syncthreads();  // all waves done with blr; next stage's vmcnt drained here too
    }

    // ---- epilogue: D lane map col = lane&15, row = (lane>>4)*4 + r ----
    const int m0 = (lane >> 4) * 4;
    const int cn = cg * 256 + (lane & 15);
#pragma unroll
    for (int mt = 0; mt < 2; ++mt) {
        long rbase = row0 + (rg * 2 + mt) * 16 + m0;
        const f32x4* accp = mt ? acc1 : acc0;
#pragma unroll
        for (int nt = 0; nt < 16; ++nt) {
            f32x4 v = accp[nt];
            int col = cn + nt * 16;
#pragma unroll
            for (int r = 0; r < 4; ++r)
                xp[(rbase + r) * H_ + col] = __float2half(v[r] + bias[nt]);
        }
    }
}

// Wave-k-slice RNN, SGPR h-broadcast, single barrier per step (round-5 structure).
__global__ __launch_bounds__(512)
void rnn_kernel(const __half* __restrict__ xp,
                const u32* __restrict__ greg,
                const u32* __restrict__ glds,
                const float* __restrict__ Wfc,
                const float* __restrict__ bfc,
                float* __restrict__ out) {
    extern __shared__ u32 lds[];
    uint4* ldsw4 = (uint4*)lds;                   // 8*512 uint4 = 65536 B
    float* part  = (float*)(lds + LCH * 512 * 4); // 2 * 8*512 f32 = 32768 B
    const int t = threadIdx.x;
    const int w = t >> 6;
    const int l = t & 63;
    const int b = blockIdx.x;

    u32 wregs[NREG];
    const uint4* greg4 = (const uint4*)greg;
#pragma unroll
    for (int i4 = 0; i4 < NCH; ++i4) {
        uint4 v = greg4[i4 * 512 + t];
        wregs[4 * i4 + 0] = v.x; wregs[4 * i4 + 1] = v.y;
        wregs[4 * i4 + 2] = v.z; wregs[4 * i4 + 3] = v.w;
    }
    const uint4* glds4 = (const uint4*)glds;
    for (int c = 0; c < LCH; ++c) ldsw4[c * 512 + t] = glds4[c * 512 + t];

    const __half* xprow = xp + (size_t)b * T_ * H_ + t;
    float xpv = __half2float(xprow[0]);
    int hp[32];
#pragma unroll
    for (int p = 0; p < 32; ++p) hp[p] = 0;  // h0 = 0
    __syncthreads();

    float hn = 0.f;
    int buf = 0;
    for (int ts = 0; ts < T_; ++ts) {
        int tn = (ts + 1 < T_) ? (ts + 1) : ts;
        __half nxt = xprow[(size_t)tn * H_];  // global prefetch, independent
        float acc[8];
#pragma unroll
        for (int q = 0; q < 8; ++q) acc[q] = 0.f;
        // resident weight pairs p in [0,28)
#pragma unroll
        for (int p = 0; p < 28; ++p) {
#pragma unroll
            for (int q = 0; q < 8; ++q)
                acc[q] = dot2f((u32)hp[p], wregs[q * 28 + p], acc[q]);
        }
        // LDS-streamed weight pairs p in [28,32): chunk ch feeds exactly acc[ch]
#pragma unroll
        for (int ch = 0; ch < LCH; ++ch) {
            uint4 v = ldsw4[ch * 512 + t];
            acc[ch] = dot2f((u32)hp[28], v.x, acc[ch]);
            acc[ch] = dot2f((u32)hp[29], v.y, acc[ch]);
            acc[ch] = dot2f((u32)hp[30], v.z, acc[ch]);
            acc[ch] = dot2f((u32)hp[31], v.w, acc[ch]);
        }
        float* pb = part + buf * 4096;
#pragma unroll
        for (int q = 0; q < 8; ++q) pb[w * 512 + l + 64 * q] = acc[q];  // 2-way alias = free
        __syncthreads();
        float s = xpv;
#pragma unroll
        for (int ww = 0; ww < 8; ++ww) s += pb[ww * 512 + t];  // coalesced
        hn = fast_tanh(s);
        xpv = __half2float(nxt);
        // redistribute h in-wave: even lane 2p holds pack(h[64w+2p], h[64w+2p+1])
        float nb = __shfl_xor(hn, 1, 64);
        u32 pair = pk2(hn, nb);
#pragma unroll
        for (int p = 0; p < 32; ++p)
            hp[p] = __builtin_amdgcn_readlane((int)pair, 2 * p);
        buf ^= 1;
    }

    // epilogue: out[b] = h_last . Wfc + bfc - 0.05  (thread t holds column t)
    __syncthreads();
    float v = hn * Wfc[t];
#pragma unroll
    for (int off = 32; off; off >>= 1) v += __shfl_down(v, off, 64);
    float* red = part;
    if (l == 0) red[w] = v;
    __syncthreads();
    if (t == 0) {
        float ssum = 0.f;
        for (int ww = 0; ww < 8; ++ww) ssum += red[ww];
        out[b] = ssum + bfc[0] - 0.05f;
    }
}

extern "C" void kernel_launch(void* const* d_in, const int* in_sizes, int n_in,
                              void* d_out, int out_size, void* d_ws, size_t ws_size,
                              hipStream_t stream) {
    const float* x   = (const float*)d_in[0];
    const float* Wx  = (const float*)d_in[1];
    const float* Wh  = (const float*)d_in[2];
    const float* b   = (const float*)d_in[3];
    const float* Wfc = (const float*)d_in[4];
    const float* bfc = (const float*)d_in[5];
    float* out = (float*)d_out;

    char* ws = (char*)d_ws;
    __half* xp  = (__half*)ws;                          // 134,217,728 B
    u32* Bg     = (u32*)(ws + 134217728);               //     262,144 B
    u32* greg   = (u32*)(ws + 134479872);               //     458,752 B
    u32* glds   = (u32*)(ws + 134938624);               //      65,536 B

    prepack_kernel<<<384, 512, 0, stream>>>(Wx, Wh, Bg, greg, glds);

    const int gemm_lds = 131072;  // 64 KB A + 2x32 KB B double-buffer
    (void)hipFuncSetAttribute((const void*)xp_mfma_kernel,
                              hipFuncAttributeMaxDynamicSharedMemorySize, gemm_lds);
    xp_mfma_kernel<<<(B_ * T_) / 128, 512, gemm_lds, stream>>>(x, (const uint4*)Bg, b, xp);

    const int dyn = LCH * 512 * 16 + 2 * 8 * 512 * 4;  // 65536 + 32768 = 98304 B
    (void)hipFuncSetAttribute((const void*)rnn_kernel,
                              hipFuncAttributeMaxDynamicSharedMemorySize, dyn);
    rnn_kernel<<<B_, 512, dyn, stream>>>(xp, greg, glds, Wfc, bfc, out);
}